// Round 5
// baseline (206.081 us; speedup 1.0000x reference)
//
#include <hip/hip_runtime.h>
#include <stdint.h>

// Haar 3D DWT: float32 in, float32 out, fp32 internal math.
// x: (2,3,16,256,256) f32
// out: LLL (2,3,15,256,256) followed by detail (2,3,105,256,256), f32.
// detail frame-axis order: LLH, LHL, LHH, HLL, HLH, HHL, HHH (15 frames each).
//
// One wave per (nc, f, h-tile of 4 rows). Frame-stage intermediates
// l = S*(x[f]+x[f+1]), g = S*(x[f+1]-x[f]) are computed once per loaded row
// (5 rows) and reused by the height stage (4 output rows) -> 10 loads for
// 4 output rows instead of 16. All 32 output float4 stores are non-temporal
// so the 189 MB write stream does not evict the reused input rows from L2.

static constexpr float S = 0.35355339059327373f;  // 1/(2*sqrt(2))
static constexpr int   PLANE = 256 * 256;          // 65536
static constexpr size_t LLL_ELEMS = (size_t)6 * 15 * PLANE;  // 5,898,240

typedef float fvec4 __attribute__((ext_vector_type(4)));

__device__ __forceinline__ void st_nt(float* p, float a, float b, float c, float d) {
    fvec4 v = {a, b, c, d};
    __builtin_nontemporal_store(v, (fvec4*)p);
}

__device__ __forceinline__ void st_lo(float* p, const float* A) {
    // width low-pass: S*(A[j] + A[j+1])
    st_nt(p, S * (A[0] + A[1]), S * (A[1] + A[2]),
             S * (A[2] + A[3]), S * (A[3] + A[4]));
}

__device__ __forceinline__ void st_hi(float* p, const float* A) {
    // width high-pass: S*(A[j+1] - A[j])
    st_nt(p, S * (A[1] - A[0]), S * (A[2] - A[1]),
             S * (A[3] - A[2]), S * (A[4] - A[3]));
}

__global__ __launch_bounds__(256) void haar3d_kernel(const float* __restrict__ x,
                                                     float* __restrict__ out) {
    const int wid  = blockIdx.x * 4 + (threadIdx.x >> 6);  // 0..5759
    const int lane = threadIdx.x & 63;
    const int hq   = wid & 63;        // h-tile index
    const int t    = wid >> 6;        // 0..89
    const int f    = t % 15;
    const int nc   = t / 15;          // 0..5
    const int h0   = hq << 2;         // 0,4,...,252
    const int w    = lane << 2;

    const float* p0 = x + ((size_t)(nc * 16 + f) * 256 + h0) * 256 + w;  // frame f
    const float* p1 = p0 + PLANE;                                        // frame f+1
    const bool lastTile = (h0 == 252);

    // ---- load 5 rows x 2 frames; fold frame stage immediately ----
    float l[5][4], g[5][4];
#pragma unroll
    for (int r = 0; r < 5; ++r) {
        float4 a = make_float4(0.f, 0.f, 0.f, 0.f);
        float4 b = a;
        if (r < 4 || !lastTile) {   // row h0+4==256 exists only when h0<252
            a = *(const float4*)(p0 + r * 256);
            b = *(const float4*)(p1 + r * 256);
        }
        l[r][0] = S * (a.x + b.x);  g[r][0] = S * (b.x - a.x);
        l[r][1] = S * (a.y + b.y);  g[r][1] = S * (b.y - a.y);
        l[r][2] = S * (a.z + b.z);  g[r][2] = S * (b.z - a.z);
        l[r][3] = S * (a.w + b.w);  g[r][3] = S * (b.w - a.w);
    }

    // ---- output bases ----
    const size_t rowOff = ((size_t)h0) * 256 + w;
    float* lllDst = out + ((size_t)(nc * 15 + f)) * PLANE + rowOff;
    float* dbase  = out + LLL_ELEMS + ((size_t)nc * 105 + f) * PLANE + rowOff;
    const size_t kStride = (size_t)15 * PLANE;
    const bool last = (lane == 63);

    // ---- height stage + width stage + stores, 4 output rows ----
#pragma unroll
    for (int r = 0; r < 4; ++r) {
        float LL[5], LH[5], HL[5], HH[5];
#pragma unroll
        for (int j = 0; j < 4; ++j) {
            LL[j] = S * (l[r][j] + l[r + 1][j]);
            LH[j] = S * (l[r + 1][j] - l[r][j]);
            HL[j] = S * (g[r][j] + g[r + 1][j]);
            HH[j] = S * (g[r + 1][j] - g[r][j]);
        }
        // width neighbor (w+4) from lane+1; lane 63 -> right zero pad
        const float nLL = __shfl_down(LL[0], 1);
        const float nLH = __shfl_down(LH[0], 1);
        const float nHL = __shfl_down(HL[0], 1);
        const float nHH = __shfl_down(HH[0], 1);
        LL[4] = last ? 0.f : nLL;
        LH[4] = last ? 0.f : nLH;
        HL[4] = last ? 0.f : nHL;
        HH[4] = last ? 0.f : nHH;

        const size_t ro = (size_t)r * 256;
        st_lo(lllDst + ro,              LL);   // LLL
        st_hi(dbase + 0 * kStride + ro, LL);   // LLH
        st_lo(dbase + 1 * kStride + ro, LH);   // LHL
        st_hi(dbase + 2 * kStride + ro, LH);   // LHH
        st_lo(dbase + 3 * kStride + ro, HL);   // HLL
        st_hi(dbase + 4 * kStride + ro, HL);   // HLH
        st_lo(dbase + 5 * kStride + ro, HH);   // HHL
        st_hi(dbase + 6 * kStride + ro, HH);   // HHH
    }
}

extern "C" void kernel_launch(void* const* d_in, const int* in_sizes, int n_in,
                              void* d_out, int out_size, void* d_ws, size_t ws_size,
                              hipStream_t stream) {
    const float* x = (const float*)d_in[0];
    float* out = (float*)d_out;
    // 6 nc * 15 f * 64 h-tiles = 5760 waves = 1440 blocks of 256 (exact)
    haar3d_kernel<<<dim3(1440), dim3(256), 0, stream>>>(x, out);
}